// Round 1
// baseline (257.853 us; speedup 1.0000x reference)
//
#include <hip/hip_runtime.h>
#include <hip/hip_bf16.h>
#include <stdint.h>

#define IN_F 1024
#define OUT_F 1024
#define NB 8
#define KDIM (IN_F + IN_F * NB)  /* 9216 */
#define NROWS 4096
#define SLICE_ELEMS (NROWS * OUT_F)
#define PREP_BLOCKS ((NROWS * IN_F) / 256)        /* 16384 */
#define WCONV_BLOCKS ((OUT_F * KDIM) / (4 * 256)) /* 9216  */

typedef __attribute__((ext_vector_type(8))) short bf16x8;
typedef __attribute__((ext_vector_type(4))) short bf16x4;
typedef __attribute__((ext_vector_type(4))) float f32x4;

// Closed-form uniform cubic B-spline (knots t_j = -2.2 + 0.4j; EPS=1e-8 shift is
// far below bf16 rounding). For x in [t_i,t_{i+1}): 4 nonzero cardinal cubics.
__device__ __forceinline__ void bspline8(float x, float b8[8]) {
  float u = (x + 2.2f) * 2.5f;  // (x - t0)/h
  bool in = (u >= 0.0f) && (u < 11.0f);
  float uc = fminf(fmaxf(u, 0.0f), 10.99f);
  int i = (int)uc;
  float f = uc - (float)i;
  float g = 1.0f - f;
  float f2 = f * f, f3 = f2 * f;
  const float s = 1.0f / 6.0f;
  float v0 = f3 * s;
  float v1 = (-3.0f * f3 + 3.0f * f2 + 3.0f * f + 1.0f) * s;
  float v2 = (3.0f * f3 - 6.0f * f2 + 4.0f) * s;
  float v3 = g * g * g * s;
#pragma unroll
  for (int j = 0; j < 8; ++j) {
    int d = i - j;
    float r = (d == 0) ? v0 : (d == 1) ? v1 : (d == 2) ? v2 : (d == 3) ? v3 : 0.0f;
    b8[j] = in ? r : 0.0f;
  }
}

// Fused prep (A build) + weight conversion, branch on blockIdx (block-uniform).
__global__ void prep_all_kernel(const float* __restrict__ x, const float* __restrict__ bw,
                                const float* __restrict__ sw, __hip_bfloat16* __restrict__ A,
                                __hip_bfloat16* __restrict__ W) {
  if (blockIdx.x < PREP_BLOCKS) {
    int idx = blockIdx.x * 256 + threadIdx.x;
    int n = idx >> 10;
    int i = idx & 1023;
    float xv = x[idx];
    float sl = xv / (1.0f + __expf(-xv));
    __hip_bfloat16* row = A + (size_t)n * KDIM;
    row[i] = __float2bfloat16(sl);
    float b8[8];
    bspline8(xv, b8);
    alignas(16) __hip_bfloat16 tmp[8];
#pragma unroll
    for (int c = 0; c < 8; ++c) tmp[c] = __float2bfloat16(b8[c]);
    *(bf16x8*)(row + IN_F + i * 8) = *(const bf16x8*)tmp;
  } else {
    int v = (blockIdx.x - PREP_BLOCKS) * 256 + threadIdx.x;
    int e = v * 4;
    int o = e / KDIM;
    int k = e - o * KDIM;
    float4 val = (k < IN_F) ? *(const float4*)(bw + o * IN_F + k)
                            : *(const float4*)(sw + (size_t)o * (IN_F * NB) + (k - IN_F));
    alignas(8) __hip_bfloat16 t[4];
    t[0] = __float2bfloat16(val.x);
    t[1] = __float2bfloat16(val.y);
    t[2] = __float2bfloat16(val.z);
    t[3] = __float2bfloat16(val.w);
    *(bf16x4*)(W + e) = *(const bf16x4*)t;
  }
}

// C = A[4096,9216] @ W[1024,9216]^T, 128x128 tile, BK=64, split-K over z.
// Double-buffered LDS (64 KB): stage tile it+1 into buf 1-p BEFORE computing on
// buf p; with BK=64 the compute phase (~32 MFMA + 16 ds_read per wave, >800 cyc)
// exceeds load latency, so the barrier's vmcnt(0) drain pays ~0.
// LDS layout per buffer: 8 row-groups x 2 k-subtiles x 512 elems in MFMA fragment
// order (lane l: row=l&15, kchunk=l>>4) -> all ds/staging addrs = wave-uniform
// base + 16B*lane: conflict-free, and legal for global_load_lds's lane scatter.
__global__ __launch_bounds__(256) void gemm_kernel(const __hip_bfloat16* __restrict__ A,
                                                   const __hip_bfloat16* __restrict__ W,
                                                   float* __restrict__ dst,
                                                   const float* __restrict__ bias,
                                                   int kslice, int use_bias) {
  __shared__ __hip_bfloat16 lA[2][128 * 64];
  __shared__ __hip_bfloat16 lB[2][128 * 64];
  const int tid = threadIdx.x;
  const int wave = tid >> 6;
  const int lane = tid & 63;
  const int bm = blockIdx.x * 128;
  const int bn = blockIdx.y * 128;
  const int z = blockIdx.z;
  float* __restrict__ d = dst + (size_t)z * SLICE_ELEMS;
  const int kbeg = z * kslice;
  const int iters = kslice / 64;
  const int srow = lane & 15;       // staging row within a 16-row group
  const int skc = (lane >> 4) * 8;  // staging k-chunk offset within a 32-k subtile
  const int wm = (wave & 1) * 64;
  const int wn = (wave >> 1) * 64;
  const int r = lane & 15;
  const int quad = lane >> 4;

  const int g0 = wave * 2;  // this wave stages row-groups g0, g0+1 of A and B
  const __hip_bfloat16* gA[2];
  const __hip_bfloat16* gB[2];
  gA[0] = A + (size_t)(bm + g0 * 16 + srow) * KDIM + kbeg + skc;
  gA[1] = gA[0] + (size_t)16 * KDIM;
  gB[0] = W + (size_t)(bn + g0 * 16 + srow) * KDIM + kbeg + skc;
  gB[1] = gB[0] + (size_t)16 * KDIM;

  f32x4 acc[4][4];
#pragma unroll
  for (int a = 0; a < 4; ++a)
#pragma unroll
    for (int b = 0; b < 4; ++b) acc[a][b] = (f32x4){0.f, 0.f, 0.f, 0.f};

#define STAGE(IT, BUF)                                                                             \
  do {                                                                                             \
    const int koff = (IT) * 64;                                                                    \
    _Pragma("unroll") for (int h = 0; h < 2; ++h) {                                                \
      _Pragma("unroll") for (int s = 0; s < 2; ++s) {                                              \
        const __hip_bfloat16* srcA = gA[h] + koff + s * 32;                                        \
        const __hip_bfloat16* srcB = gB[h] + koff + s * 32;                                        \
        __hip_bfloat16* dA = &lA[BUF][((g0 + h) * 2 + s) * 512];                                   \
        __hip_bfloat16* dB = &lB[BUF][((g0 + h) * 2 + s) * 512];                                   \
        __builtin_amdgcn_global_load_lds((const __attribute__((address_space(1))) void*)srcA,      \
                                         (__attribute__((address_space(3))) void*)dA, 16, 0, 0);   \
        __builtin_amdgcn_global_load_lds((const __attribute__((address_space(1))) void*)srcB,      \
                                         (__attribute__((address_space(3))) void*)dB, 16, 0, 0);   \
      }                                                                                            \
    }                                                                                              \
  } while (0)

  STAGE(0, 0);
  __syncthreads();

  for (int it = 0; it < iters; ++it) {
    const int p = it & 1;
    if (it + 1 < iters) STAGE(it + 1, p ^ 1);  // in flight across the whole compute phase

#pragma unroll
    for (int s = 0; s < 2; ++s) {
      bf16x8 af[4], bfr[4];
#pragma unroll
      for (int t = 0; t < 4; ++t) {
        af[t] = *(const bf16x8*)&lA[p][(((wm >> 4) + t) * 2 + s) * 512 + lane * 8];
        bfr[t] = *(const bf16x8*)&lB[p][(((wn >> 4) + t) * 2 + s) * 512 + lane * 8];
      }
#pragma unroll
      for (int tm = 0; tm < 4; ++tm)
#pragma unroll
        for (int tn = 0; tn < 4; ++tn)
          acc[tm][tn] =
              __builtin_amdgcn_mfma_f32_16x16x32_bf16(af[tm], bfr[tn], acc[tm][tn], 0, 0, 0);
    }

    __syncthreads();  // drains vmcnt (tile it+1 staged) + all waves done reading buf p
  }
#undef STAGE

  // C/D map: col=lane&15, row=quad*4+reg (m89-verified).
#pragma unroll
  for (int tm = 0; tm < 4; ++tm) {
#pragma unroll
    for (int tn = 0; tn < 4; ++tn) {
      const int col = bn + wn + tn * 16 + r;
      const float bv = use_bias ? bias[col] : 0.0f;
#pragma unroll
      for (int reg = 0; reg < 4; ++reg) {
        const int rowi = bm + wm + tm * 16 + quad * 4 + reg;
        d[(size_t)rowi * OUT_F + col] = acc[tm][tn][reg] + bv;
      }
    }
  }
}

// out = bias + sum_s partial[s], float4 per thread.
__global__ void reduce_kernel(const float* __restrict__ P, const float* __restrict__ bias,
                              float* __restrict__ out, int S) {
  int v = blockIdx.x * 256 + threadIdx.x;
  int e = v * 4;
  int o = e & (OUT_F - 1);
  float4 acc = *(const float4*)(bias + o);
  for (int s = 0; s < S; ++s) {
    float4 p = *(const float4*)(P + (size_t)s * SLICE_ELEMS + e);
    acc.x += p.x;
    acc.y += p.y;
    acc.z += p.z;
    acc.w += p.w;
  }
  *(float4*)(out + e) = acc;
}

// Emergency fallback if ws is too small for A+W (fp32, slow but correct).
__global__ void kan_fallback(const float* __restrict__ x, const float* __restrict__ bw,
                             const float* __restrict__ bb, const float* __restrict__ sw,
                             float* __restrict__ out) {
  __shared__ float act[KDIM];
  int n = blockIdx.x;
  for (int i = threadIdx.x; i < IN_F; i += 256) {
    float xv = x[(size_t)n * IN_F + i];
    act[i] = xv / (1.0f + __expf(-xv));
    float b8[8];
    bspline8(xv, b8);
#pragma unroll
    for (int c = 0; c < 8; ++c) act[IN_F + i * 8 + c] = b8[c];
  }
  __syncthreads();
  for (int o = threadIdx.x; o < OUT_F; o += 256) {
    float s = bb[o];
    const float* wbp = bw + (size_t)o * IN_F;
    for (int k = 0; k < IN_F; ++k) s += act[k] * wbp[k];
    const float* wsp = sw + (size_t)o * (IN_F * NB);
    for (int k = 0; k < IN_F * NB; ++k) s += act[IN_F + k] * wsp[k];
    out[(size_t)n * OUT_F + o] = s;
  }
}

extern "C" void kernel_launch(void* const* d_in, const int* in_sizes, int n_in, void* d_out,
                              int out_size, void* d_ws, size_t ws_size, hipStream_t stream) {
  const float* x = (const float*)d_in[0];
  const float* bw = (const float*)d_in[1];
  const float* bb = (const float*)d_in[2];
  const float* sw = (const float*)d_in[3];
  float* out = (float*)d_out;

  const size_t needA = (size_t)NROWS * KDIM * 2;  // 75.5 MB
  const size_t needW = (size_t)OUT_F * KDIM * 2;  // 18.9 MB
  const size_t sliceB = (size_t)SLICE_ELEMS * 4;  // 16.8 MB
  if (ws_size < needA + needW) {
    kan_fallback<<<NROWS, 256, 0, stream>>>(x, bw, bb, sw, out);
    return;
  }
  __hip_bfloat16* A = (__hip_bfloat16*)d_ws;
  __hip_bfloat16* W = (__hip_bfloat16*)((char*)d_ws + needA);
  float* P = (float*)((char*)d_ws + needA + needW);
  const size_t avail = ws_size - needA - needW;
  int S = (avail >= 2 * sliceB) ? 2 : 1;  // 512 blocks -> 2 blocks/CU

  prep_all_kernel<<<PREP_BLOCKS + WCONV_BLOCKS, 256, 0, stream>>>(x, bw, sw, A, W);
  if (S == 1) {
    gemm_kernel<<<dim3(NROWS / 128, OUT_F / 128, 1), 256, 0, stream>>>(A, W, out, bb, KDIM, 1);
  } else {
    gemm_kernel<<<dim3(NROWS / 128, OUT_F / 128, S), 256, 0, stream>>>(A, W, P, bb, KDIM / S, 0);
    reduce_kernel<<<SLICE_ELEMS / (4 * 256), 256, 0, stream>>>(P, bb, out, S);
  }
}

// Round 2
// 219.379 us; speedup vs baseline: 1.1754x; 1.1754x over previous
//
#include <hip/hip_runtime.h>
#include <hip/hip_bf16.h>
#include <stdint.h>

#define IN_F 1024
#define OUT_F 1024
#define NB 8
#define KDIM (IN_F + IN_F * NB)  /* 9216 */
#define NROWS 4096
#define SLICE_ELEMS (NROWS * OUT_F)
#define PREP_BLOCKS ((NROWS * IN_F) / 256)        /* 16384 */
#define WCONV_BLOCKS ((OUT_F * KDIM) / (4 * 256)) /* 9216  */

typedef __attribute__((ext_vector_type(8))) short bf16x8;
typedef __attribute__((ext_vector_type(4))) short bf16x4;
typedef __attribute__((ext_vector_type(4))) float f32x4;

// Closed-form uniform cubic B-spline (knots t_j = -2.2 + 0.4j; EPS=1e-8 shift is
// far below bf16 rounding). For x in [t_i,t_{i+1}): 4 nonzero cardinal cubics.
__device__ __forceinline__ void bspline8(float x, float b8[8]) {
  float u = (x + 2.2f) * 2.5f;  // (x - t0)/h
  bool in = (u >= 0.0f) && (u < 11.0f);
  float uc = fminf(fmaxf(u, 0.0f), 10.99f);
  int i = (int)uc;
  float f = uc - (float)i;
  float g = 1.0f - f;
  float f2 = f * f, f3 = f2 * f;
  const float s = 1.0f / 6.0f;
  float v0 = f3 * s;
  float v1 = (-3.0f * f3 + 3.0f * f2 + 3.0f * f + 1.0f) * s;
  float v2 = (3.0f * f3 - 6.0f * f2 + 4.0f) * s;
  float v3 = g * g * g * s;
#pragma unroll
  for (int j = 0; j < 8; ++j) {
    int d = i - j;
    float r = (d == 0) ? v0 : (d == 1) ? v1 : (d == 2) ? v2 : (d == 3) ? v3 : 0.0f;
    b8[j] = in ? r : 0.0f;
  }
}

// Fused prep (A build) + weight conversion, branch on blockIdx (block-uniform).
__global__ void prep_all_kernel(const float* __restrict__ x, const float* __restrict__ bw,
                                const float* __restrict__ sw, __hip_bfloat16* __restrict__ A,
                                __hip_bfloat16* __restrict__ W) {
  if (blockIdx.x < PREP_BLOCKS) {
    int idx = blockIdx.x * 256 + threadIdx.x;
    int n = idx >> 10;
    int i = idx & 1023;
    float xv = x[idx];
    float sl = xv / (1.0f + __expf(-xv));
    __hip_bfloat16* row = A + (size_t)n * KDIM;
    row[i] = __float2bfloat16(sl);
    float b8[8];
    bspline8(xv, b8);
    alignas(16) __hip_bfloat16 tmp[8];
#pragma unroll
    for (int c = 0; c < 8; ++c) tmp[c] = __float2bfloat16(b8[c]);
    *(bf16x8*)(row + IN_F + i * 8) = *(const bf16x8*)tmp;
  } else {
    int v = (blockIdx.x - PREP_BLOCKS) * 256 + threadIdx.x;
    int e = v * 4;
    int o = e / KDIM;
    int k = e - o * KDIM;
    float4 val = (k < IN_F) ? *(const float4*)(bw + o * IN_F + k)
                            : *(const float4*)(sw + (size_t)o * (IN_F * NB) + (k - IN_F));
    alignas(8) __hip_bfloat16 t[4];
    t[0] = __float2bfloat16(val.x);
    t[1] = __float2bfloat16(val.y);
    t[2] = __float2bfloat16(val.z);
    t[3] = __float2bfloat16(val.w);
    *(bf16x4*)(W + e) = *(const bf16x4*)t;
  }
}

// ---------------------------------------------------------------------------
// 256x256-tile, BK=64, 8-wave (2Mx4N), 8-phase K-loop with counted vmcnt (T3+T4)
// and setprio around MFMA clusters (T5). Ported from the m201 template shape;
// LDS kept in MFMA-fragment order (global gather via per-lane global_load_lds
// source addrs) so ds_reads are conflict-free without an XOR swizzle (T2-free).
//
// LDS: lA[slot][g*2+s][512], g=row-group 0..15 (16 rows each), s=k-subtile
// (32k each). slot = K-tile parity. 2*(32KB+32KB) = 128 KB -> 1 block/CU.
//
// Per K-tile, per wave: 24 ds_read_b128 front-loaded {P1:16 (A m0-3 + all B),
// P2:8 (A m4-7), P3:0, P4:0}; so B-halves are dead after P1, A-halves after P2.
// Stage ledger per iter i (computes t=2i in P1-4 slot0, t=2i+1 in P5-8 slot1);
// each stage targets a half whose last ds_read retired >=1 phase before
// (enforced by per-phase barrier + lgkmcnt(0)):
//   P1: t(2i+1).A1->sl1   (dead since prev P6)
//   P2: t(2i+2).B0->sl0   (B dead after P1)
//   P3: t(2i+2).B1->sl0
//   P4: t(2i+2).A0->sl0   (A dead after P2)   + vmcnt(6)
//   P5: t(2i+2).A1->sl0
//   P6: t(2i+3).B0->sl1   (slot1 B dead after P5)
//   P7: t(2i+3).B1->sl1
//   P8: t(2i+3).A0->sl1   (slot1 A dead after P6) + vmcnt(6)
// vmcnt(6)=3 half-tiles (6 loads/wave) in flight. At P4: lands t(2i+1).A1 ->
// slot1 complete before P5. At P8: lands t(2i+2).{B0,B1,A0,A1} -> slot0
// complete before next P1. Tail: source-tile clamped to NT-1 (same-dest
// same-data rewrite, count math preserved). Prologue: 7 halves, vmcnt(6)
// lands t0's 4 halves.
// ---------------------------------------------------------------------------
__global__ __launch_bounds__(512, 2) void gemm8_kernel(const __hip_bfloat16* __restrict__ A,
                                                       const __hip_bfloat16* __restrict__ W,
                                                       float* __restrict__ dst,
                                                       const float* __restrict__ bias,
                                                       int kslice, int use_bias) {
  __shared__ __hip_bfloat16 lA[2][16384];
  __shared__ __hip_bfloat16 lB[2][16384];
  const int tid = threadIdx.x;
  const int wave = tid >> 6;
  const int lane = tid & 63;
  const int warp_m = wave >> 2;  // 0..1 -> 128-row half
  const int warp_n = wave & 3;   // 0..3 -> 64-col quarter
  const int bm = blockIdx.x * 256;
  const int bn = blockIdx.y * 256;
  const int z = blockIdx.z;
  float* __restrict__ d = dst + (size_t)z * SLICE_ELEMS;
  const int kbeg = z * kslice;
  const int NT = kslice >> 6;   // K-tiles of 64
  const int NIT = NT >> 1;      // 2 K-tiles per iteration
  const int srow = lane & 15;
  const int skc = (lane >> 4) * 8;
  const int r = lane & 15;
  const int quad = lane >> 4;

  // per-wave global row bases for the halves it stages (A/B halves 0,1)
  const __hip_bfloat16* rowA[2];
  const __hip_bfloat16* rowB[2];
  rowA[0] = A + (size_t)(bm + (0 * 8 + wave) * 16 + srow) * KDIM + kbeg + skc;
  rowA[1] = A + (size_t)(bm + (1 * 8 + wave) * 16 + srow) * KDIM + kbeg + skc;
  rowB[0] = W + (size_t)(bn + (0 * 8 + wave) * 16 + srow) * KDIM + kbeg + skc;
  rowB[1] = W + (size_t)(bn + (1 * 8 + wave) * 16 + srow) * KDIM + kbeg + skc;

  f32x4 acc[8][4];
#pragma unroll
  for (int a = 0; a < 8; ++a)
#pragma unroll
    for (int b = 0; b < 4; ++b) acc[a][b] = (f32x4){0.f, 0.f, 0.f, 0.f};

#define GLOAD(SRC, DST)                                                                      \
  __builtin_amdgcn_global_load_lds((const __attribute__((address_space(1))) void*)(SRC),     \
                                   (__attribute__((address_space(3))) void*)(DST), 16, 0, 0)

  // HID: 0=A-half0, 1=A-half1, 2=B-half0, 3=B-half1. SLOT explicit.
#define STAGE_HALF(TILE, HID, SLOT)                                              \
  do {                                                                           \
    const int tu_ = (TILE);                                                      \
    const int ts_ = tu_ < NT ? tu_ : NT - 1;                                     \
    if ((HID) < 2) {                                                             \
      const __hip_bfloat16* s_ = rowA[(HID)] + (size_t)ts_ * 64;                 \
      __hip_bfloat16* d_ = &lA[(SLOT)][(((HID) * 8 + wave) * 2 + 0) * 512];      \
      GLOAD(s_, d_);                                                             \
      GLOAD(s_ + 32, d_ + 512);                                                  \
    } else {                                                                     \
      const __hip_bfloat16* s_ = rowB[(HID) - 2] + (size_t)ts_ * 64;             \
      __hip_bfloat16* d_ = &lB[(SLOT)][((((HID) - 2) * 8 + wave) * 2 + 0) * 512];\
      GLOAD(s_, d_);                                                             \
      GLOAD(s_ + 32, d_ + 512);                                                  \
    }                                                                            \
  } while (0)

  bf16x8 a03[4][2], a47[4][2], bfr[4][2];

#define LOAD_A03(SLOT)                                                                      \
  do {                                                                                      \
    _Pragma("unroll") for (int t = 0; t < 4; ++t) {                                         \
      a03[t][0] = *(const bf16x8*)&lA[(SLOT)][((warp_m * 8 + t) * 2 + 0) * 512 + lane * 8]; \
      a03[t][1] = *(const bf16x8*)&lA[(SLOT)][((warp_m * 8 + t) * 2 + 1) * 512 + lane * 8]; \
    }                                                                                       \
  } while (0)
#define LOAD_A47(SLOT)                                                                          \
  do {                                                                                          \
    _Pragma("unroll") for (int t = 0; t < 4; ++t) {                                             \
      a47[t][0] = *(const bf16x8*)&lA[(SLOT)][((warp_m * 8 + 4 + t) * 2 + 0) * 512 + lane * 8]; \
      a47[t][1] = *(const bf16x8*)&lA[(SLOT)][((warp_m * 8 + 4 + t) * 2 + 1) * 512 + lane * 8]; \
    }                                                                                           \
  } while (0)
#define LOAD_B(SLOT)                                                                        \
  do {                                                                                      \
    _Pragma("unroll") for (int u = 0; u < 4; ++u) {                                         \
      bfr[u][0] = *(const bf16x8*)&lB[(SLOT)][((warp_n * 4 + u) * 2 + 0) * 512 + lane * 8]; \
      bfr[u][1] = *(const bf16x8*)&lB[(SLOT)][((warp_n * 4 + u) * 2 + 1) * 512 + lane * 8]; \
    }                                                                                       \
  } while (0)

#define MFMA_QUAD(AF, TM0, TN0)                                                              \
  do {                                                                                       \
    _Pragma("unroll") for (int tm = 0; tm < 4; ++tm)                                         \
    _Pragma("unroll") for (int tn = 0; tn < 2; ++tn)                                         \
    _Pragma("unroll") for (int s = 0; s < 2; ++s)                                            \
        acc[(TM0) + tm][(TN0) + tn] = __builtin_amdgcn_mfma_f32_16x16x32_bf16(               \
            AF[tm][s], bfr[(TN0) + tn][s], acc[(TM0) + tm][(TN0) + tn], 0, 0, 0);            \
  } while (0)

#define PH_BAR_LGKM()                                        \
  do {                                                       \
    __builtin_amdgcn_s_barrier();                            \
    asm volatile("s_waitcnt lgkmcnt(0)" ::: "memory");       \
    __builtin_amdgcn_sched_barrier(0);                       \
  } while (0)
#define PH_BAR()                                             \
  do {                                                       \
    __builtin_amdgcn_s_barrier();                            \
    __builtin_amdgcn_sched_barrier(0);                       \
  } while (0)
#define PH_END()                                             \
  do {                                                       \
    __builtin_amdgcn_s_setprio(0);                           \
    __builtin_amdgcn_sched_barrier(0);                       \
    __builtin_amdgcn_s_barrier();                            \
  } while (0)

  // ---- prologue: t0 fully, t1 all but A1; land t0 ----
  STAGE_HALF(0, 2, 0);
  STAGE_HALF(0, 3, 0);
  STAGE_HALF(0, 0, 0);
  STAGE_HALF(0, 1, 0);
  STAGE_HALF(1, 2, 1);
  STAGE_HALF(1, 3, 1);
  STAGE_HALF(1, 0, 1);
  asm volatile("s_waitcnt vmcnt(6)" ::: "memory");
  __builtin_amdgcn_sched_barrier(0);
  __builtin_amdgcn_s_barrier();

  for (int i = 0; i < NIT; ++i) {
    const int t2 = 2 * i + 2, t3 = 2 * i + 3;
    // ---- P1: K-tile 2i (slot0), quadrant (m0-3, n0-1) ----
    LOAD_A03(0);
    LOAD_B(0);
    STAGE_HALF(2 * i + 1, 1, 1);
    PH_BAR_LGKM();
    __builtin_amdgcn_s_setprio(1);
    MFMA_QUAD(a03, 0, 0);
    PH_END();
    // ---- P2: (m4-7, n0-1) ----
    LOAD_A47(0);
    STAGE_HALF(t2, 2, 0);
    PH_BAR_LGKM();
    __builtin_amdgcn_s_setprio(1);
    MFMA_QUAD(a47, 4, 0);
    PH_END();
    // ---- P3: (m0-3, n2-3) ----
    STAGE_HALF(t2, 3, 0);
    PH_BAR();
    __builtin_amdgcn_s_setprio(1);
    MFMA_QUAD(a03, 0, 2);
    PH_END();
    // ---- P4: (m4-7, n2-3) ----
    STAGE_HALF(t2, 0, 0);
    asm volatile("s_waitcnt vmcnt(6)" ::: "memory");
    __builtin_amdgcn_sched_barrier(0);
    PH_BAR();
    __builtin_amdgcn_s_setprio(1);
    MFMA_QUAD(a47, 4, 2);
    PH_END();
    // ---- P5: K-tile 2i+1 (slot1), (m0-3, n0-1) ----
    LOAD_A03(1);
    LOAD_B(1);
    STAGE_HALF(t2, 1, 0);
    PH_BAR_LGKM();
    __builtin_amdgcn_s_setprio(1);
    MFMA_QUAD(a03, 0, 0);
    PH_END();
    // ---- P6: (m4-7, n0-1) ----
    LOAD_A47(1);
    STAGE_HALF(t3, 2, 1);
    PH_BAR_LGKM();
    __builtin_amdgcn_s_setprio(1);
    MFMA_QUAD(a47, 4, 0);
    PH_END();
    // ---- P7: (m0-3, n2-3) ----
    STAGE_HALF(t3, 3, 1);
    PH_BAR();
    __builtin_amdgcn_s_setprio(1);
    MFMA_QUAD(a03, 0, 2);
    PH_END();
    // ---- P8: (m4-7, n2-3) ----
    STAGE_HALF(t3, 0, 1);
    asm volatile("s_waitcnt vmcnt(6)" ::: "memory");
    __builtin_amdgcn_sched_barrier(0);
    PH_BAR();
    __builtin_amdgcn_s_setprio(1);
    MFMA_QUAD(a47, 4, 2);
    PH_END();
  }
  asm volatile("s_waitcnt vmcnt(0)" ::: "memory");

#undef STAGE_HALF
#undef GLOAD
#undef LOAD_A03
#undef LOAD_A47
#undef LOAD_B
#undef MFMA_QUAD
#undef PH_BAR_LGKM
#undef PH_BAR
#undef PH_END

  // C/D map: col=lane&15, row=quad*4+reg (m89-verified).
#pragma unroll
  for (int tm = 0; tm < 8; ++tm) {
#pragma unroll
    for (int tn = 0; tn < 4; ++tn) {
      const int col = bn + warp_n * 64 + tn * 16 + r;
      const float bv = use_bias ? bias[col] : 0.0f;
#pragma unroll
      for (int reg = 0; reg < 4; ++reg) {
        const int rowi = bm + warp_m * 128 + tm * 16 + quad * 4 + reg;
        d[(size_t)rowi * OUT_F + col] = acc[tm][tn][reg] + bv;
      }
    }
  }
}

// out = bias + sum_s partial[s], float4 per thread.
__global__ void reduce_kernel(const float* __restrict__ P, const float* __restrict__ bias,
                              float* __restrict__ out, int S) {
  int v = blockIdx.x * 256 + threadIdx.x;
  int e = v * 4;
  int o = e & (OUT_F - 1);
  float4 acc = *(const float4*)(bias + o);
  for (int s = 0; s < S; ++s) {
    float4 p = *(const float4*)(P + (size_t)s * SLICE_ELEMS + e);
    acc.x += p.x;
    acc.y += p.y;
    acc.z += p.z;
    acc.w += p.w;
  }
  *(float4*)(out + e) = acc;
}

// Emergency fallback if ws is too small for A+W (fp32, slow but correct).
__global__ void kan_fallback(const float* __restrict__ x, const float* __restrict__ bw,
                             const float* __restrict__ bb, const float* __restrict__ sw,
                             float* __restrict__ out) {
  __shared__ float act[KDIM];
  int n = blockIdx.x;
  for (int i = threadIdx.x; i < IN_F; i += 256) {
    float xv = x[(size_t)n * IN_F + i];
    act[i] = xv / (1.0f + __expf(-xv));
    float b8[8];
    bspline8(xv, b8);
#pragma unroll
    for (int c = 0; c < 8; ++c) act[IN_F + i * 8 + c] = b8[c];
  }
  __syncthreads();
  for (int o = threadIdx.x; o < OUT_F; o += 256) {
    float s = bb[o];
    const float* wbp = bw + (size_t)o * IN_F;
    for (int k = 0; k < IN_F; ++k) s += act[k] * wbp[k];
    const float* wsp = sw + (size_t)o * (IN_F * NB);
    for (int k = 0; k < IN_F * NB; ++k) s += act[IN_F + k] * wsp[k];
    out[(size_t)n * OUT_F + o] = s;
  }
}

extern "C" void kernel_launch(void* const* d_in, const int* in_sizes, int n_in, void* d_out,
                              int out_size, void* d_ws, size_t ws_size, hipStream_t stream) {
  const float* x = (const float*)d_in[0];
  const float* bw = (const float*)d_in[1];
  const float* bb = (const float*)d_in[2];
  const float* sw = (const float*)d_in[3];
  float* out = (float*)d_out;

  const size_t needA = (size_t)NROWS * KDIM * 2;  // 75.5 MB
  const size_t needW = (size_t)OUT_F * KDIM * 2;  // 18.9 MB
  const size_t sliceB = (size_t)SLICE_ELEMS * 4;  // 16.8 MB
  if (ws_size < needA + needW) {
    kan_fallback<<<NROWS, 256, 0, stream>>>(x, bw, bb, sw, out);
    return;
  }
  __hip_bfloat16* A = (__hip_bfloat16*)d_ws;
  __hip_bfloat16* W = (__hip_bfloat16*)((char*)d_ws + needA);
  float* P = (float*)((char*)d_ws + needA + needW);
  const size_t avail = ws_size - needA - needW;
  // S=4 -> 16x4x4 = 256 blocks = 1 block/CU (128 KB LDS). kslice=2304, NT=36.
  int S = (avail >= 4 * sliceB) ? 4 : (avail >= 2 * sliceB) ? 2 : 1;

  prep_all_kernel<<<PREP_BLOCKS + WCONV_BLOCKS, 256, 0, stream>>>(x, bw, sw, A, W);
  if (S == 1) {
    gemm8_kernel<<<dim3(NROWS / 256, OUT_F / 256, 1), 512, 0, stream>>>(A, W, out, bb, KDIM, 1);
  } else {
    gemm8_kernel<<<dim3(NROWS / 256, OUT_F / 256, S), 512, 0, stream>>>(A, W, P, bb, KDIM / S, 0);
    reduce_kernel<<<SLICE_ELEMS / (4 * 256), 256, 0, stream>>>(P, bb, out, S);
  }
}